// Round 6
// baseline (238.731 us; speedup 1.0000x reference)
//
#include <hip/hip_runtime.h>

#define Bn 16
#define Hn 512
#define Wn 512
#define RAD 24
#define WPR 16  // 32-bit words per row (Wn/32)

typedef _Float16 h2 __attribute__((ext_vector_type(2)));

// ---------------------------------------------------------------------------
// K_A: fused binarize + morphology + column-bitmap transpose.
// Block = (b, 32-row group w). Produces:
//   mbits[b][row][16]  mask bits (for BCE t)
//   cbits[b][col][16]  boundary bits column-major: word w = rows 32w..32w+31
// Also zeroes the accumulator pair (block 0).
// ---------------------------------------------------------------------------
__global__ __launch_bounds__(256) void k_prep(
    const float* __restrict__ tgt, unsigned int* __restrict__ mbits,
    unsigned int* __restrict__ cbits, unsigned long long* __restrict__ acc,
    unsigned int* __restrict__ done) {
  __shared__ unsigned int lm[36][16];   // mask bits rows y0-2..y0+33
  __shared__ unsigned int bnd[32][16];  // boundary bits rows y0..y0+31
  const int w = blockIdx.x & 15, b = blockIdx.x >> 4;
  const int y0 = w * 32;
  const int t = threadIdx.x;
  const int lane = t & 63;

  if (blockIdx.x == 0 && t == 0) {
    *acc = 0ull;
    *done = 0u;
  }

  // binarize 36 rows x 512 cols via ballot (72 uniform iterations)
  for (int it = 0; it < 72; ++it) {
    int idx = it * 256 + t;  // 0..18431
    int r = idx >> 9, c = idx & 511;
    int y = y0 - 2 + r;
    float v = (y >= 0 && y < Hn) ? tgt[((size_t)b * Hn + y) * Wn + c] : 0.0f;
    unsigned long long m = __ballot(v > 0.5f);
    if ((lane & 31) == 0)
      lm[r][c >> 5] =
          (unsigned int)(lane == 0 ? (m & 0xffffffffull) : (m >> 32));
  }
  __syncthreads();

  // word-parallel morphology: boundary = dilate3(mask & ~erode3(mask))
  for (int task = t; task < 512; task += 256) {
    int rr = task >> 4, k = task & 15;  // output row y0+rr, word k
    unsigned int m[5][5];
#pragma unroll
    for (int dy = 0; dy < 5; ++dy)
#pragma unroll
      for (int dx = 0; dx < 5; ++dx) {
        int wi = k + dx - 2;
        m[dy][dx] = (wi >= 0 && wi < 16) ? lm[rr + dy][wi] : 0u;
      }
    unsigned int hb[5][3];
#pragma unroll
    for (int dy = 0; dy < 5; ++dy)
#pragma unroll
      for (int dx = 0; dx < 3; ++dx) {
        unsigned int l = m[dy][dx], c = m[dy][dx + 1], r2 = m[dy][dx + 2];
        hb[dy][dx] = c & ((c << 1) | (l >> 31)) & ((c >> 1) | (r2 << 31));
      }
    unsigned int D = 0;
#pragma unroll
    for (int dy = 1; dy <= 3; ++dy) {
      unsigned int C[3];
#pragma unroll
      for (int dx = 0; dx < 3; ++dx) {
        unsigned int E = hb[dy - 1][dx] & hb[dy][dx] & hb[dy + 1][dx];
        C[dx] = m[dy][dx + 1] & ~E;
      }
      D |= C[1] | ((C[1] << 1) | (C[0] >> 31)) | ((C[1] >> 1) | (C[2] << 31));
    }
    bnd[rr][k] = D;
  }
  __syncthreads();

  // ballot-transpose: 2 cols per ballot (lane = (colpair<<5)|row)
  {
    const int wv = t >> 6;
    const int r = lane & 31;
    for (int it = 0; it < 64; ++it) {
      int cp = it * 4 + wv;            // col pair 0..255
      int c = cp * 2 + (lane >> 5);    // col
      unsigned int bit = (bnd[r][c >> 5] >> (c & 31)) & 1u;
      unsigned long long m = __ballot(bit != 0);
      if (lane == 0) {
        size_t base = ((size_t)b * Wn + cp * 2) * WPR + w;
        cbits[base] = (unsigned int)(m & 0xffffffffull);
        cbits[base + WPR] = (unsigned int)(m >> 32);
      }
    }
  }

  // write mask bits (rows y0..y0+31)
  for (int task = t; task < 512; task += 256) {
    int r = task >> 4, wi = task & 15;
    mbits[((size_t)b * Hn + y0 + r) * WPR + wi] = lm[2 + r][wi];
  }
}

// ---------------------------------------------------------------------------
// vertical distance from column bit-words (5 words cover rows i-64..i+95)
// ---------------------------------------------------------------------------
__device__ __forceinline__ int dv_from(unsigned int W0, unsigned int W1,
                                       unsigned int W2, unsigned int W3,
                                       unsigned int W4, int q) {
  unsigned int mLE = (q == 31) ? W2 : (W2 & ((1u << (q + 1)) - 1u));
  int up = mLE ? (q - 31 + __clz(mLE))
               : (W1 ? (q + 1 + __clz(W1))
                     : (W0 ? (q + 33 + __clz(W0)) : 255));
  unsigned int Wd = W2 >> q;
  int down = Wd ? (__ffs(Wd) - 1)
                : (W3 ? (31 - q + __ffs(W3))
                      : (W4 ? (63 - q + __ffs(W4)) : 255));
  return min(up, down);
}

// ---------------------------------------------------------------------------
// K_B: chamfer window (f16-paired rows, wave-uniform early exit), BCE,
// fixed-point atomic reduce; last block writes the mean.
// ---------------------------------------------------------------------------
__global__ __launch_bounds__(256) void k_loss(
    const float* __restrict__ x, const unsigned int* __restrict__ mbits,
    const unsigned int* __restrict__ cbits, unsigned long long* __restrict__ acc,
    unsigned int* __restrict__ done, float* __restrict__ out) {
  __shared__ h2 dvs[304];  // entry e: rows (i0, i0+1) at col c0+e-RAD
  __shared__ float red[4];
  const int cx = blockIdx.x, by = blockIdx.y, b = blockIdx.z;
  const int i0 = 2 * by;
  const int c0 = cx * 256;
  const int tx = threadIdx.x;
  const size_t row0 = ((size_t)b * Hn + i0) * Wn;
  const int wq = i0 >> 5, q = i0 & 31;  // q even, q+1 <= 31

  for (int e = tx; e < 304; e += 256) {
    int c = c0 + e - RAD;
    int dv0 = 255, dv1 = 255;
    if (c >= 0 && c < Wn) {
      const unsigned int* cw = cbits + ((size_t)b * Wn + c) * WPR;
      unsigned int W0 = (wq >= 2) ? cw[wq - 2] : 0u;
      unsigned int W1 = (wq >= 1) ? cw[wq - 1] : 0u;
      unsigned int W2 = cw[wq];
      unsigned int W3 = (wq <= 14) ? cw[wq + 1] : 0u;
      unsigned int W4 = (wq <= 13) ? cw[wq + 2] : 0u;
      dv0 = dv_from(W0, W1, W2, W3, W4, q);
      dv1 = dv_from(W0, W1, W2, W3, W4, q + 1);
    }
    h2 pk;
    pk.x = (_Float16)(float)dv0;
    pk.y = (_Float16)(float)dv1;
    dvs[e] = pk;
  }
  __syncthreads();

  const h2 A2 = {(_Float16)0.955f, (_Float16)0.955f};
  const h2 BA2 = {(_Float16)0.4143f, (_Float16)0.4143f};
  h2 acc0 = {(_Float16)300.0f, (_Float16)300.0f};
  h2 acc1 = acc0;

#define STEP(k)                                                              \
  {                                                                          \
    const h2 c1 = {(_Float16)(0.955f * (k)), (_Float16)(0.955f * (k))};      \
    const h2 c2 = {(_Float16)(0.4143f * (k)), (_Float16)(0.4143f * (k))};    \
    h2 v = __builtin_elementwise_min(dvs[tx + RAD - (k)],                    \
                                     dvs[tx + RAD + (k)]);                   \
    h2 f = __builtin_elementwise_max(v * BA2 + c1, v * A2 + c2);             \
    if ((k) & 1) acc1 = __builtin_elementwise_min(acc1, f);                  \
    else         acc0 = __builtin_elementwise_min(acc0, f);                  \
  }

#define CHECK(kn)                                                            \
  {                                                                          \
    h2 qq = __builtin_elementwise_min(acc0, acc1);                           \
    float mm = fmaxf((float)qq.x, (float)qq.y);                              \
    for (int s = 1; s < 64; s <<= 1) mm = fmaxf(mm, __shfl_xor(mm, s, 64));  \
    if (0.955f * (float)(kn) >= mm) goto done_lab;                           \
  }

  STEP(0) STEP(1) STEP(2) STEP(3) STEP(4) STEP(5) STEP(6) STEP(7) STEP(8)
  CHECK(9)
  STEP(9) STEP(10) STEP(11) STEP(12)
  CHECK(13)
  STEP(13) STEP(14) STEP(15) STEP(16)
  CHECK(17)
  STEP(17) STEP(18) STEP(19) STEP(20)
  CHECK(21)
  STEP(21) STEP(22) STEP(23) STEP(24)
done_lab:;

  h2 am = __builtin_elementwise_min(acc0, acc1);
  float d0 = (float)am.x, d1 = (float)am.y;
  float w0 = __expf(d0 * (-1.0f / 3.0f)) + 0.1f;
  float w1 = __expf(d1 * (-1.0f / 3.0f)) + 0.1f;

  const int col = c0 + tx;
  const int wi = col >> 5, sh = col & 31;
  unsigned int mw0 = mbits[((size_t)b * Hn + i0) * WPR + wi];
  unsigned int mw1 = mbits[((size_t)b * Hn + i0 + 1) * WPR + wi];
  float t0 = (float)((mw0 >> sh) & 1u);
  float t1 = (float)((mw1 >> sh) & 1u);

  float L0 = x[row0 + col], L1 = x[row0 + Wn + col];
  L0 = fminf(fmaxf(L0, -16.118095f), 16.118095f);
  L1 = fminf(fmaxf(L1, -16.118095f), 16.118095f);
  float bce0 = fmaxf(L0, 0.0f) - L0 * t0 + __logf(1.0f + __expf(-fabsf(L0)));
  float bce1 = fmaxf(L1, 0.0f) - L1 * t1 + __logf(1.0f + __expf(-fabsf(L1)));
  float val = bce0 * w0 + bce1 * w1;

#pragma unroll
  for (int s = 32; s; s >>= 1) val += __shfl_down(val, s, 64);
  if ((tx & 63) == 0) red[tx >> 6] = val;
  __syncthreads();
  if (tx == 0) {
    float s = red[0] + red[1] + red[2] + red[3];
    unsigned long long qv =
        (unsigned long long)__double2ll_rn((double)s * 1048576.0);
    atomicAdd(acc, qv);
    __threadfence();
    unsigned int old = atomicAdd(done, 1u);
    if (old == (2u * (Hn / 2) * Bn) - 1u) {
      __threadfence();
      unsigned long long total = atomicAdd(acc, 0ull);
      out[0] = (float)((double)total / (1048576.0 * (double)((size_t)Bn * Hn * Wn)));
    }
  }
}

extern "C" void kernel_launch(void* const* d_in, const int* in_sizes, int n_in,
                              void* d_out, int out_size, void* d_ws, size_t ws_size,
                              hipStream_t stream) {
  const float* inputs = (const float*)d_in[0];
  const float* targets = (const float*)d_in[1];
  float* out = (float*)d_out;

  unsigned char* ws = (unsigned char*)d_ws;
  unsigned int* mbits = (unsigned int*)ws;                        // 512 KB
  unsigned int* cbits = (unsigned int*)(ws + (512 << 10));        // 512 KB
  unsigned long long* acc = (unsigned long long*)(ws + (1 << 20));
  unsigned int* done = (unsigned int*)(ws + (1 << 20) + 8);

  hipLaunchKernelGGL(k_prep, dim3(Bn * 16), dim3(256), 0, stream, targets,
                     mbits, cbits, acc, done);
  {
    dim3 blk(256, 1, 1), grd(2, Hn / 2, Bn);
    hipLaunchKernelGGL(k_loss, grd, blk, 0, stream, inputs, mbits, cbits, acc,
                       done, out);
  }
}

// Round 7
// 58.495 us; speedup vs baseline: 4.0812x; 4.0812x over previous
//
#include <hip/hip_runtime.h>

#define Bn 16
#define Hn 512
#define Wn 512
#define RAD 24
#define WPR 16  // 32-bit words per row (Wn/32)

typedef _Float16 h2 __attribute__((ext_vector_type(2)));

// ---------------------------------------------------------------------------
// K_A: fused binarize + morphology + column-bitmap transpose.
// Block = (b, 32-row group w). Produces:
//   mbits[b][row][16]   mask bits (for BCE t)
//   cbits[b][w][col]    boundary bits, word-major: plane w = rows 32w..32w+31
// ---------------------------------------------------------------------------
__global__ __launch_bounds__(256) void k_prep(
    const float* __restrict__ tgt, unsigned int* __restrict__ mbits,
    unsigned int* __restrict__ cbits) {
  __shared__ unsigned int lm[36][16];   // mask bits rows y0-2..y0+33
  __shared__ unsigned int bnd[32][16];  // boundary bits rows y0..y0+31
  const int w = blockIdx.x & 15, b = blockIdx.x >> 4;
  const int y0 = w * 32;
  const int t = threadIdx.x;
  const int lane = t & 63;

  // binarize 36 rows x 512 cols via ballot (72 uniform iterations)
  for (int it = 0; it < 72; ++it) {
    int idx = it * 256 + t;  // 0..18431
    int r = idx >> 9, c = idx & 511;
    int y = y0 - 2 + r;
    float v = (y >= 0 && y < Hn) ? tgt[((size_t)b * Hn + y) * Wn + c] : 0.0f;
    unsigned long long m = __ballot(v > 0.5f);
    if ((lane & 31) == 0)
      lm[r][c >> 5] =
          (unsigned int)(lane == 0 ? (m & 0xffffffffull) : (m >> 32));
  }
  __syncthreads();

  // word-parallel morphology: boundary = dilate3(mask & ~erode3(mask))
  for (int task = t; task < 512; task += 256) {
    int rr = task >> 4, k = task & 15;  // output row y0+rr, word k
    unsigned int m[5][5];
#pragma unroll
    for (int dy = 0; dy < 5; ++dy)
#pragma unroll
      for (int dx = 0; dx < 5; ++dx) {
        int wi = k + dx - 2;
        m[dy][dx] = (wi >= 0 && wi < 16) ? lm[rr + dy][wi] : 0u;
      }
    unsigned int hb[5][3];
#pragma unroll
    for (int dy = 0; dy < 5; ++dy)
#pragma unroll
      for (int dx = 0; dx < 3; ++dx) {
        unsigned int l = m[dy][dx], c = m[dy][dx + 1], r2 = m[dy][dx + 2];
        hb[dy][dx] = c & ((c << 1) | (l >> 31)) & ((c >> 1) | (r2 << 31));
      }
    unsigned int D = 0;
#pragma unroll
    for (int dy = 1; dy <= 3; ++dy) {
      unsigned int C[3];
#pragma unroll
      for (int dx = 0; dx < 3; ++dx) {
        unsigned int E = hb[dy - 1][dx] & hb[dy][dx] & hb[dy + 1][dx];
        C[dx] = m[dy][dx + 1] & ~E;
      }
      D |= C[1] | ((C[1] << 1) | (C[0] >> 31)) | ((C[1] >> 1) | (C[2] << 31));
    }
    bnd[rr][k] = D;
  }
  __syncthreads();

  // ballot-transpose: 2 cols per ballot (lane = (col-half<<5)|row)
  {
    const int wv = t >> 6;
    const int r = lane & 31;
    for (int it = 0; it < 64; ++it) {
      int cp = it * 4 + wv;            // col pair 0..255
      int c = cp * 2 + (lane >> 5);    // col
      unsigned int bit = (bnd[r][c >> 5] >> (c & 31)) & 1u;
      unsigned long long m = __ballot(bit != 0);
      if (lane == 0) {
        size_t base = ((size_t)b * WPR + w) * Wn + cp * 2;
        cbits[base] = (unsigned int)(m & 0xffffffffull);
        cbits[base + 1] = (unsigned int)(m >> 32);
      }
    }
  }

  // write mask bits (rows y0..y0+31)
  for (int task = t; task < 512; task += 256) {
    int r = task >> 4, wi = task & 15;
    mbits[((size_t)b * Hn + y0 + r) * WPR + wi] = lm[2 + r][wi];
  }
}

// ---------------------------------------------------------------------------
// vertical distance from column bit-words (5 words cover rows i-64..i+95)
// ---------------------------------------------------------------------------
__device__ __forceinline__ int dv_from(unsigned int W0, unsigned int W1,
                                       unsigned int W2, unsigned int W3,
                                       unsigned int W4, int q) {
  unsigned int mLE = (q == 31) ? W2 : (W2 & ((1u << (q + 1)) - 1u));
  int up = mLE ? (q - 31 + __clz(mLE))
               : (W1 ? (q + 1 + __clz(W1))
                     : (W0 ? (q + 33 + __clz(W0)) : 255));
  unsigned int Wd = W2 >> q;
  int down = Wd ? (__ffs(Wd) - 1)
                : (W3 ? (31 - q + __ffs(W3))
                      : (W4 ? (63 - q + __ffs(W4)) : 255));
  return min(up, down);
}

// ---------------------------------------------------------------------------
// K_B: chamfer window (f16-paired rows, wave-uniform early exit), BCE,
// per-block partial sum (NO device-scope atomics/fences — they L2-thrash).
// ---------------------------------------------------------------------------
__global__ __launch_bounds__(256) void k_loss(
    const float* __restrict__ x, const unsigned int* __restrict__ mbits,
    const unsigned int* __restrict__ cbits, float* __restrict__ partial) {
  __shared__ h2 dvs[304];  // entry e: rows (i0, i0+1) at col c0+e-RAD
  __shared__ float red[4];
  const int cx = blockIdx.x, by = blockIdx.y, b = blockIdx.z;
  const int i0 = 2 * by;
  const int c0 = cx * 256;
  const int tx = threadIdx.x;
  const size_t row0 = ((size_t)b * Hn + i0) * Wn;
  const int wq = i0 >> 5, q = i0 & 31;  // q even, q+1 <= 31
  const unsigned int* cw = cbits + (size_t)b * WPR * Wn;

  for (int e = tx; e < 304; e += 256) {
    int c = c0 + e - RAD;
    int dv0 = 255, dv1 = 255;
    if (c >= 0 && c < Wn) {
      unsigned int W0 = (wq >= 2) ? cw[(size_t)(wq - 2) * Wn + c] : 0u;
      unsigned int W1 = (wq >= 1) ? cw[(size_t)(wq - 1) * Wn + c] : 0u;
      unsigned int W2 = cw[(size_t)wq * Wn + c];
      unsigned int W3 = (wq <= 14) ? cw[(size_t)(wq + 1) * Wn + c] : 0u;
      unsigned int W4 = (wq <= 13) ? cw[(size_t)(wq + 2) * Wn + c] : 0u;
      dv0 = dv_from(W0, W1, W2, W3, W4, q);
      dv1 = dv_from(W0, W1, W2, W3, W4, q + 1);
    }
    h2 pk;
    pk.x = (_Float16)(float)dv0;
    pk.y = (_Float16)(float)dv1;
    dvs[e] = pk;
  }
  __syncthreads();

  const h2 A2 = {(_Float16)0.955f, (_Float16)0.955f};
  const h2 BA2 = {(_Float16)0.4143f, (_Float16)0.4143f};
  h2 acc0 = {(_Float16)300.0f, (_Float16)300.0f};
  h2 acc1 = acc0;

#define STEP(k)                                                              \
  {                                                                          \
    const h2 c1 = {(_Float16)(0.955f * (k)), (_Float16)(0.955f * (k))};      \
    const h2 c2 = {(_Float16)(0.4143f * (k)), (_Float16)(0.4143f * (k))};    \
    h2 v = __builtin_elementwise_min(dvs[tx + RAD - (k)],                    \
                                     dvs[tx + RAD + (k)]);                   \
    h2 f = __builtin_elementwise_max(v * BA2 + c1, v * A2 + c2);             \
    if ((k) & 1) acc1 = __builtin_elementwise_min(acc1, f);                  \
    else         acc0 = __builtin_elementwise_min(acc0, f);                  \
  }

#define CHECK(kn)                                                            \
  {                                                                          \
    h2 qq = __builtin_elementwise_min(acc0, acc1);                           \
    float mm = fmaxf((float)qq.x, (float)qq.y);                              \
    for (int s = 1; s < 64; s <<= 1) mm = fmaxf(mm, __shfl_xor(mm, s, 64));  \
    if (0.955f * (float)(kn) >= mm) goto done_lab;                           \
  }

  STEP(0) STEP(1) STEP(2) STEP(3) STEP(4) STEP(5) STEP(6) STEP(7) STEP(8)
  CHECK(9)
  STEP(9) STEP(10) STEP(11) STEP(12)
  CHECK(13)
  STEP(13) STEP(14) STEP(15) STEP(16)
  CHECK(17)
  STEP(17) STEP(18) STEP(19) STEP(20)
  CHECK(21)
  STEP(21) STEP(22) STEP(23) STEP(24)
done_lab:;

  h2 am = __builtin_elementwise_min(acc0, acc1);
  float d0 = (float)am.x, d1 = (float)am.y;
  float w0 = __expf(d0 * (-1.0f / 3.0f)) + 0.1f;
  float w1 = __expf(d1 * (-1.0f / 3.0f)) + 0.1f;

  const int col = c0 + tx;
  const int wi = col >> 5, sh = col & 31;
  unsigned int mw0 = mbits[((size_t)b * Hn + i0) * WPR + wi];
  unsigned int mw1 = mbits[((size_t)b * Hn + i0 + 1) * WPR + wi];
  float t0 = (float)((mw0 >> sh) & 1u);
  float t1 = (float)((mw1 >> sh) & 1u);

  float L0 = x[row0 + col], L1 = x[row0 + Wn + col];
  L0 = fminf(fmaxf(L0, -16.118095f), 16.118095f);
  L1 = fminf(fmaxf(L1, -16.118095f), 16.118095f);
  float bce0 = fmaxf(L0, 0.0f) - L0 * t0 + __logf(1.0f + __expf(-fabsf(L0)));
  float bce1 = fmaxf(L1, 0.0f) - L1 * t1 + __logf(1.0f + __expf(-fabsf(L1)));
  float val = bce0 * w0 + bce1 * w1;

#pragma unroll
  for (int s = 32; s; s >>= 1) val += __shfl_down(val, s, 64);
  if ((tx & 63) == 0) red[tx >> 6] = val;
  __syncthreads();
  if (tx == 0)
    partial[(((b << 8) + by) << 1) + cx] = red[0] + red[1] + red[2] + red[3];
}

// ---------------------------------------------------------------------------
// K_C: deterministic final reduction (double accumulation) -> mean.
// ---------------------------------------------------------------------------
__global__ __launch_bounds__(1024) void k_final(
    const float* __restrict__ partial, float* __restrict__ out) {
  __shared__ double red[1024];
  double s = 0.0;
  for (int idx = threadIdx.x; idx < Bn * 512; idx += 1024)
    s += (double)partial[idx];
  red[threadIdx.x] = s;
  __syncthreads();
  for (int st = 512; st; st >>= 1) {
    if (threadIdx.x < st) red[threadIdx.x] += red[threadIdx.x + st];
    __syncthreads();
  }
  if (threadIdx.x == 0)
    out[0] = (float)(red[0] / (double)((size_t)Bn * Hn * Wn));
}

extern "C" void kernel_launch(void* const* d_in, const int* in_sizes, int n_in,
                              void* d_out, int out_size, void* d_ws, size_t ws_size,
                              hipStream_t stream) {
  const float* inputs = (const float*)d_in[0];
  const float* targets = (const float*)d_in[1];
  float* out = (float*)d_out;

  unsigned char* ws = (unsigned char*)d_ws;
  unsigned int* mbits = (unsigned int*)ws;                        // 512 KB
  unsigned int* cbits = (unsigned int*)(ws + (512 << 10));        // 512 KB
  float* partial = (float*)(ws + (1 << 20));                      // 32 KB

  hipLaunchKernelGGL(k_prep, dim3(Bn * 16), dim3(256), 0, stream, targets,
                     mbits, cbits);
  {
    dim3 blk(256, 1, 1), grd(2, Hn / 2, Bn);
    hipLaunchKernelGGL(k_loss, grd, blk, 0, stream, inputs, mbits, cbits,
                       partial);
  }
  hipLaunchKernelGGL(k_final, dim3(1), dim3(1024), 0, stream, partial, out);
}

// Round 8
// 39.460 us; speedup vs baseline: 6.0500x; 1.4824x over previous
//
#include <hip/hip_runtime.h>

#define Bn 16
#define Hn 512
#define Wn 512
#define RAD 24
#define WPR 16  // 32-bit words per row (Wn/32)

typedef _Float16 h2 __attribute__((ext_vector_type(2)));

// ---------------------------------------------------------------------------
// K0: binarize targets -> 1 bit/px (mbits). 2048 blocks, float4 coalesced.
// Block covers 4 rows (2048 floats).
// ---------------------------------------------------------------------------
__global__ __launch_bounds__(256) void k_pack(
    const float* __restrict__ tgt, unsigned int* __restrict__ mbits) {
  __shared__ int nib[512];
  const int tid = threadIdx.x;
  const size_t base4 = (size_t)blockIdx.x * 512;
  const float4* t4 = (const float4*)tgt;
#pragma unroll
  for (int j = 0; j < 2; ++j) {
    float4 v = t4[base4 + tid + 256 * j];
    int n = (v.x > 0.5f ? 1 : 0) | (v.y > 0.5f ? 2 : 0) |
            (v.z > 0.5f ? 4 : 0) | (v.w > 0.5f ? 8 : 0);
    nib[tid + 256 * j] = n;
  }
  __syncthreads();
  if (tid < 64) {
    unsigned int w = 0;
#pragma unroll
    for (int c = 0; c < 8; ++c)
      w |= ((unsigned int)nib[8 * tid + c]) << (4 * c);
    mbits[(size_t)blockIdx.x * 64 + tid] = w;
  }
}

// ---------------------------------------------------------------------------
// K1: word-parallel morphology on mbits + transpose to column bitmap.
// Block = (b, 32-row group w). cbits[b][w][col]: bit r = boundary(row 32w+r).
// Reads only 2.3 KB/block of mbits (L2-resident) — latency-tolerant.
// ---------------------------------------------------------------------------
__global__ __launch_bounds__(256) void k_morphT(
    const unsigned int* __restrict__ mbits, unsigned int* __restrict__ cbits) {
  __shared__ unsigned int lm[36][16];   // mask rows y0-2..y0+33
  __shared__ unsigned int bnd[32][17];  // boundary bits, padded (no conflicts)
  const int w = blockIdx.x & 15, b = blockIdx.x >> 4;
  const int y0 = w * 32;
  const int t = threadIdx.x;

  for (int idx = t; idx < 36 * 16; idx += 256) {
    int r = idx >> 4, wi = idx & 15;
    int y = y0 - 2 + r;
    lm[r][wi] = (y >= 0 && y < Hn) ? mbits[((size_t)b * Hn + y) * WPR + wi] : 0u;
  }
  __syncthreads();

  for (int task = t; task < 512; task += 256) {
    int rr = task >> 4, k = task & 15;  // output row y0+rr, word k
    unsigned int m[5][5];
#pragma unroll
    for (int dy = 0; dy < 5; ++dy)
#pragma unroll
      for (int dx = 0; dx < 5; ++dx) {
        int wi = k + dx - 2;
        m[dy][dx] = (wi >= 0 && wi < 16) ? lm[rr + dy][wi] : 0u;
      }
    unsigned int hb[5][3];
#pragma unroll
    for (int dy = 0; dy < 5; ++dy)
#pragma unroll
      for (int dx = 0; dx < 3; ++dx) {
        unsigned int l = m[dy][dx], c = m[dy][dx + 1], r2 = m[dy][dx + 2];
        hb[dy][dx] = c & ((c << 1) | (l >> 31)) & ((c >> 1) | (r2 << 31));
      }
    unsigned int D = 0;
#pragma unroll
    for (int dy = 1; dy <= 3; ++dy) {
      unsigned int C[3];
#pragma unroll
      for (int dx = 0; dx < 3; ++dx) {
        unsigned int E = hb[dy - 1][dx] & hb[dy][dx] & hb[dy + 1][dx];
        C[dx] = m[dy][dx + 1] & ~E;
      }
      D |= C[1] | ((C[1] << 1) | (C[0] >> 31)) | ((C[1] >> 1) | (C[2] << 31));
    }
    bnd[rr][k] = D;
  }
  __syncthreads();

  // transpose: per-thread bit assembly, LDS broadcast reads, coalesced writes
#pragma unroll
  for (int cc = 0; cc < 2; ++cc) {
    int col = t + 256 * cc;
    unsigned int bw = 0;
#pragma unroll
    for (int r = 0; r < 32; ++r)
      bw |= ((bnd[r][col >> 5] >> (col & 31)) & 1u) << r;
    cbits[((size_t)b * WPR + w) * Wn + col] = bw;
  }
}

// ---------------------------------------------------------------------------
// vertical distance from column bit-words (5 words cover rows i-64..i+95)
// ---------------------------------------------------------------------------
__device__ __forceinline__ int dv_from(unsigned int W0, unsigned int W1,
                                       unsigned int W2, unsigned int W3,
                                       unsigned int W4, int q) {
  unsigned int mLE = (q == 31) ? W2 : (W2 & ((1u << (q + 1)) - 1u));
  int up = mLE ? (q - 31 + __clz(mLE))
               : (W1 ? (q + 1 + __clz(W1))
                     : (W0 ? (q + 33 + __clz(W0)) : 255));
  unsigned int Wd = W2 >> q;
  int down = Wd ? (__ffs(Wd) - 1)
                : (W3 ? (31 - q + __ffs(W3))
                      : (W4 ? (63 - q + __ffs(W4)) : 255));
  return min(up, down);
}

// ---------------------------------------------------------------------------
// K2: chamfer window (f16-paired rows, wave-uniform early exit), BCE,
// per-block partial sum (NO device-scope atomics/fences — they L2-thrash).
// ---------------------------------------------------------------------------
__global__ __launch_bounds__(256) void k_loss(
    const float* __restrict__ x, const unsigned int* __restrict__ mbits,
    const unsigned int* __restrict__ cbits, float* __restrict__ partial) {
  __shared__ h2 dvs[304];  // entry e: rows (i0, i0+1) at col c0+e-RAD
  __shared__ float red[4];
  const int cx = blockIdx.x, by = blockIdx.y, b = blockIdx.z;
  const int i0 = 2 * by;
  const int c0 = cx * 256;
  const int tx = threadIdx.x;
  const size_t row0 = ((size_t)b * Hn + i0) * Wn;
  const int wq = i0 >> 5, q = i0 & 31;  // q even, q+1 <= 31
  const unsigned int* cw = cbits + (size_t)b * WPR * Wn;

  for (int e = tx; e < 304; e += 256) {
    int c = c0 + e - RAD;
    int dv0 = 255, dv1 = 255;
    if (c >= 0 && c < Wn) {
      unsigned int W0 = (wq >= 2) ? cw[(size_t)(wq - 2) * Wn + c] : 0u;
      unsigned int W1 = (wq >= 1) ? cw[(size_t)(wq - 1) * Wn + c] : 0u;
      unsigned int W2 = cw[(size_t)wq * Wn + c];
      unsigned int W3 = (wq <= 14) ? cw[(size_t)(wq + 1) * Wn + c] : 0u;
      unsigned int W4 = (wq <= 13) ? cw[(size_t)(wq + 2) * Wn + c] : 0u;
      dv0 = dv_from(W0, W1, W2, W3, W4, q);
      dv1 = dv_from(W0, W1, W2, W3, W4, q + 1);
    }
    h2 pk;
    pk.x = (_Float16)(float)dv0;
    pk.y = (_Float16)(float)dv1;
    dvs[e] = pk;
  }
  __syncthreads();

  const h2 A2 = {(_Float16)0.955f, (_Float16)0.955f};
  const h2 BA2 = {(_Float16)0.4143f, (_Float16)0.4143f};
  h2 acc0 = {(_Float16)300.0f, (_Float16)300.0f};
  h2 acc1 = acc0;

#define STEP(k)                                                              \
  {                                                                          \
    const h2 c1 = {(_Float16)(0.955f * (k)), (_Float16)(0.955f * (k))};      \
    const h2 c2 = {(_Float16)(0.4143f * (k)), (_Float16)(0.4143f * (k))};    \
    h2 v = __builtin_elementwise_min(dvs[tx + RAD - (k)],                    \
                                     dvs[tx + RAD + (k)]);                   \
    h2 f = __builtin_elementwise_max(v * BA2 + c1, v * A2 + c2);             \
    if ((k) & 1) acc1 = __builtin_elementwise_min(acc1, f);                  \
    else         acc0 = __builtin_elementwise_min(acc0, f);                  \
  }

#define CHECK(kn)                                                            \
  {                                                                          \
    h2 qq = __builtin_elementwise_min(acc0, acc1);                           \
    float mm = fmaxf((float)qq.x, (float)qq.y);                              \
    for (int s = 1; s < 64; s <<= 1) mm = fmaxf(mm, __shfl_xor(mm, s, 64));  \
    if (0.955f * (float)(kn) >= mm) goto done_lab;                           \
  }

  STEP(0) STEP(1) STEP(2) STEP(3) STEP(4) STEP(5) STEP(6) STEP(7) STEP(8)
  CHECK(9)
  STEP(9) STEP(10) STEP(11) STEP(12)
  CHECK(13)
  STEP(13) STEP(14) STEP(15) STEP(16)
  CHECK(17)
  STEP(17) STEP(18) STEP(19) STEP(20)
  CHECK(21)
  STEP(21) STEP(22) STEP(23) STEP(24)
done_lab:;

  h2 am = __builtin_elementwise_min(acc0, acc1);
  float d0 = (float)am.x, d1 = (float)am.y;
  float w0 = __expf(d0 * (-1.0f / 3.0f)) + 0.1f;
  float w1 = __expf(d1 * (-1.0f / 3.0f)) + 0.1f;

  const int col = c0 + tx;
  const int wi = col >> 5, sh = col & 31;
  unsigned int mw0 = mbits[((size_t)b * Hn + i0) * WPR + wi];
  unsigned int mw1 = mbits[((size_t)b * Hn + i0 + 1) * WPR + wi];
  float t0 = (float)((mw0 >> sh) & 1u);
  float t1 = (float)((mw1 >> sh) & 1u);

  float L0 = x[row0 + col], L1 = x[row0 + Wn + col];
  L0 = fminf(fmaxf(L0, -16.118095f), 16.118095f);
  L1 = fminf(fmaxf(L1, -16.118095f), 16.118095f);
  float bce0 = fmaxf(L0, 0.0f) - L0 * t0 + __logf(1.0f + __expf(-fabsf(L0)));
  float bce1 = fmaxf(L1, 0.0f) - L1 * t1 + __logf(1.0f + __expf(-fabsf(L1)));
  float val = bce0 * w0 + bce1 * w1;

#pragma unroll
  for (int s = 32; s; s >>= 1) val += __shfl_down(val, s, 64);
  if ((tx & 63) == 0) red[tx >> 6] = val;
  __syncthreads();
  if (tx == 0)
    partial[(((b << 8) + by) << 1) + cx] = red[0] + red[1] + red[2] + red[3];
}

// ---------------------------------------------------------------------------
// K3: deterministic final reduction (double accumulation) -> mean.
// ---------------------------------------------------------------------------
__global__ __launch_bounds__(1024) void k_final(
    const float* __restrict__ partial, float* __restrict__ out) {
  __shared__ double red[1024];
  double s = 0.0;
  for (int idx = threadIdx.x; idx < Bn * 512; idx += 1024)
    s += (double)partial[idx];
  red[threadIdx.x] = s;
  __syncthreads();
  for (int st = 512; st; st >>= 1) {
    if (threadIdx.x < st) red[threadIdx.x] += red[threadIdx.x + st];
    __syncthreads();
  }
  if (threadIdx.x == 0)
    out[0] = (float)(red[0] / (double)((size_t)Bn * Hn * Wn));
}

extern "C" void kernel_launch(void* const* d_in, const int* in_sizes, int n_in,
                              void* d_out, int out_size, void* d_ws, size_t ws_size,
                              hipStream_t stream) {
  const float* inputs = (const float*)d_in[0];
  const float* targets = (const float*)d_in[1];
  float* out = (float*)d_out;

  unsigned char* ws = (unsigned char*)d_ws;
  unsigned int* mbits = (unsigned int*)ws;                        // 512 KB
  unsigned int* cbits = (unsigned int*)(ws + (512 << 10));        // 512 KB
  float* partial = (float*)(ws + (1 << 20));                      // 32 KB

  hipLaunchKernelGGL(k_pack, dim3(2048), dim3(256), 0, stream, targets, mbits);
  hipLaunchKernelGGL(k_morphT, dim3(Bn * 16), dim3(256), 0, stream, mbits,
                     cbits);
  {
    dim3 blk(256, 1, 1), grd(2, Hn / 2, Bn);
    hipLaunchKernelGGL(k_loss, grd, blk, 0, stream, inputs, mbits, cbits,
                       partial);
  }
  hipLaunchKernelGGL(k_final, dim3(1), dim3(1024), 0, stream, partial, out);
}

// Round 9
// 32.298 us; speedup vs baseline: 7.3914x; 1.2217x over previous
//
#include <hip/hip_runtime.h>

#define Bn 16
#define Hn 512
#define Wn 512
#define RAD 24
#define WPR 16  // 32-bit words per row (Wn/32)

typedef _Float16 h2 __attribute__((ext_vector_type(2)));

// ---------------------------------------------------------------------------
// K0: fused binarize + morphology + transpose. Block = (b, 32-row group w),
// 1024 threads. Float4 coalesced loads (no cross-lane ops in load path),
// LDS-nibble binarize, word-parallel morphology, column-bitmap transpose.
//   mbits[b][row][16]  mask bits (BCE t)
//   cbits[b][w][col]   boundary bits word-major: bit r = boundary(row 32w+r)
// ---------------------------------------------------------------------------
__global__ __launch_bounds__(1024) void k_prep(
    const float* __restrict__ tgt, unsigned int* __restrict__ mbits,
    unsigned int* __restrict__ cbits) {
  __shared__ int nib[4608];             // 36 rows x 128 nibbles
  __shared__ unsigned int lm[36][16];   // mask words, rows y0-2..y0+33
  __shared__ unsigned int bnd[32][17];  // boundary bits, padded
  const int w = blockIdx.x & 15, b = blockIdx.x >> 4;
  const int y0 = w * 32;
  const int t = threadIdx.x;
  const float4* t4 = (const float4*)(tgt + (size_t)b * Hn * Wn);

  // binarize 36 rows x 512 cols (independent float4 loads -> pipelined)
  for (int idx = t; idx < 4608; idx += 1024) {
    int r = idx >> 7, c4 = idx & 127;
    int y = y0 - 2 + r;
    int n = 0;
    if (y >= 0 && y < Hn) {
      float4 v = t4[(size_t)y * 128 + c4];
      n = (v.x > 0.5f ? 1 : 0) | (v.y > 0.5f ? 2 : 0) |
          (v.z > 0.5f ? 4 : 0) | (v.w > 0.5f ? 8 : 0);
    }
    nib[idx] = n;
  }
  __syncthreads();

  // assemble 32-bit mask words
  for (int idx = t; idx < 576; idx += 1024) {
    int r = idx >> 4, wi = idx & 15;
    unsigned int wv = 0;
#pragma unroll
    for (int c = 0; c < 8; ++c)
      wv |= ((unsigned int)nib[(r << 7) + (wi << 3) + c]) << (4 * c);
    lm[r][wi] = wv;
  }
  __syncthreads();

  if (t < 512) {
    // word-parallel morphology: boundary = dilate3(mask & ~erode3(mask))
    int rr = t >> 4, k = t & 15;  // output row y0+rr, word k
    unsigned int m[5][5];
#pragma unroll
    for (int dy = 0; dy < 5; ++dy)
#pragma unroll
      for (int dx = 0; dx < 5; ++dx) {
        int wi = k + dx - 2;
        m[dy][dx] = (wi >= 0 && wi < 16) ? lm[rr + dy][wi] : 0u;
      }
    unsigned int hb[5][3];
#pragma unroll
    for (int dy = 0; dy < 5; ++dy)
#pragma unroll
      for (int dx = 0; dx < 3; ++dx) {
        unsigned int l = m[dy][dx], c = m[dy][dx + 1], r2 = m[dy][dx + 2];
        hb[dy][dx] = c & ((c << 1) | (l >> 31)) & ((c >> 1) | (r2 << 31));
      }
    unsigned int D = 0;
#pragma unroll
    for (int dy = 1; dy <= 3; ++dy) {
      unsigned int C[3];
#pragma unroll
      for (int dx = 0; dx < 3; ++dx) {
        unsigned int E = hb[dy - 1][dx] & hb[dy][dx] & hb[dy + 1][dx];
        C[dx] = m[dy][dx + 1] & ~E;
      }
      D |= C[1] | ((C[1] << 1) | (C[0] >> 31)) | ((C[1] >> 1) | (C[2] << 31));
    }
    bnd[rr][k] = D;
  } else {
    // concurrently write mask bits (rows y0..y0+31) — only needs lm
    int task = t - 512;
    int r = task >> 4, wi = task & 15;
    mbits[((size_t)b * Hn + y0 + r) * WPR + wi] = lm[2 + r][wi];
  }
  __syncthreads();

  // transpose: per-thread bit assembly (broadcast LDS reads), coalesced write
  if (t < 512) {
    int col = t;
    unsigned int bw = 0;
#pragma unroll
    for (int r = 0; r < 32; ++r)
      bw |= ((bnd[r][col >> 5] >> (col & 31)) & 1u) << r;
    cbits[((size_t)b * WPR + w) * Wn + col] = bw;
  }
}

// ---------------------------------------------------------------------------
// vertical distance from column bit-words (5 words cover rows i-64..i+95)
// ---------------------------------------------------------------------------
__device__ __forceinline__ int dv_from(unsigned int W0, unsigned int W1,
                                       unsigned int W2, unsigned int W3,
                                       unsigned int W4, int q) {
  unsigned int mLE = (q == 31) ? W2 : (W2 & ((1u << (q + 1)) - 1u));
  int up = mLE ? (q - 31 + __clz(mLE))
               : (W1 ? (q + 1 + __clz(W1))
                     : (W0 ? (q + 33 + __clz(W0)) : 255));
  unsigned int Wd = W2 >> q;
  int down = Wd ? (__ffs(Wd) - 1)
                : (W3 ? (31 - q + __ffs(W3))
                      : (W4 ? (63 - q + __ffs(W4)) : 255));
  return min(up, down);
}

// ---------------------------------------------------------------------------
// K1: chamfer window, 4 rows/block (two h2 pairs), wave-uniform early exit,
// BCE, per-block partial sum. Same 5 column-words serve all 4 rows.
// ---------------------------------------------------------------------------
__global__ __launch_bounds__(256) void k_loss(
    const float* __restrict__ x, const unsigned int* __restrict__ mbits,
    const unsigned int* __restrict__ cbits, float* __restrict__ partial) {
  __shared__ h2 dvsA[304];  // rows (i0, i0+1)
  __shared__ h2 dvsB[304];  // rows (i0+2, i0+3)
  __shared__ float red[4];
  const int cx = blockIdx.x, by = blockIdx.y, b = blockIdx.z;
  const int i0 = 4 * by;
  const int c0 = cx * 256;
  const int tx = threadIdx.x;
  const size_t row0 = ((size_t)b * Hn + i0) * Wn;
  const int wq = i0 >> 5, q = i0 & 31;  // q in {0,4,..,28}; q+3 <= 31
  const unsigned int* cw = cbits + (size_t)b * WPR * Wn;

  // issue x / mbits loads early; they retire under the window loop
  const int col = c0 + tx;
  float L0 = x[row0 + col];
  float L1 = x[row0 + Wn + col];
  float L2 = x[row0 + 2 * Wn + col];
  float L3 = x[row0 + 3 * Wn + col];
  const int wi = col >> 5, sh = col & 31;
  const size_t mrow = ((size_t)b * Hn + i0) * WPR + wi;
  unsigned int mw0 = mbits[mrow];
  unsigned int mw1 = mbits[mrow + WPR];
  unsigned int mw2 = mbits[mrow + 2 * WPR];
  unsigned int mw3 = mbits[mrow + 3 * WPR];

  for (int e = tx; e < 304; e += 256) {
    int c = c0 + e - RAD;
    int dv0 = 255, dv1 = 255, dv2 = 255, dv3 = 255;
    if (c >= 0 && c < Wn) {
      unsigned int W0 = (wq >= 2) ? cw[(size_t)(wq - 2) * Wn + c] : 0u;
      unsigned int W1 = (wq >= 1) ? cw[(size_t)(wq - 1) * Wn + c] : 0u;
      unsigned int W2 = cw[(size_t)wq * Wn + c];
      unsigned int W3 = (wq <= 14) ? cw[(size_t)(wq + 1) * Wn + c] : 0u;
      unsigned int W4 = (wq <= 13) ? cw[(size_t)(wq + 2) * Wn + c] : 0u;
      dv0 = dv_from(W0, W1, W2, W3, W4, q);
      dv1 = dv_from(W0, W1, W2, W3, W4, q + 1);
      dv2 = dv_from(W0, W1, W2, W3, W4, q + 2);
      dv3 = dv_from(W0, W1, W2, W3, W4, q + 3);
    }
    h2 pa, pb;
    pa.x = (_Float16)(float)dv0;
    pa.y = (_Float16)(float)dv1;
    pb.x = (_Float16)(float)dv2;
    pb.y = (_Float16)(float)dv3;
    dvsA[e] = pa;
    dvsB[e] = pb;
  }
  __syncthreads();

  const h2 A2 = {(_Float16)0.955f, (_Float16)0.955f};
  const h2 BA2 = {(_Float16)0.4143f, (_Float16)0.4143f};
  h2 a0 = {(_Float16)300.0f, (_Float16)300.0f};
  h2 a1 = a0, b0 = a0, b1 = a0;

#define STEP(k)                                                              \
  {                                                                          \
    const h2 c1 = {(_Float16)(0.955f * (k)), (_Float16)(0.955f * (k))};      \
    const h2 c2 = {(_Float16)(0.4143f * (k)), (_Float16)(0.4143f * (k))};    \
    h2 vA = __builtin_elementwise_min(dvsA[tx + RAD - (k)],                  \
                                      dvsA[tx + RAD + (k)]);                 \
    h2 vB = __builtin_elementwise_min(dvsB[tx + RAD - (k)],                  \
                                      dvsB[tx + RAD + (k)]);                 \
    h2 fA = __builtin_elementwise_max(vA * BA2 + c1, vA * A2 + c2);          \
    h2 fB = __builtin_elementwise_max(vB * BA2 + c1, vB * A2 + c2);          \
    if ((k) & 1) {                                                           \
      a1 = __builtin_elementwise_min(a1, fA);                                \
      b1 = __builtin_elementwise_min(b1, fB);                                \
    } else {                                                                 \
      a0 = __builtin_elementwise_min(a0, fA);                                \
      b0 = __builtin_elementwise_min(b0, fB);                                \
    }                                                                        \
  }

#define CHECK(kn)                                                            \
  {                                                                          \
    h2 qa = __builtin_elementwise_min(a0, a1);                               \
    h2 qb = __builtin_elementwise_min(b0, b1);                               \
    float mm = fmaxf(fmaxf((float)qa.x, (float)qa.y),                        \
                     fmaxf((float)qb.x, (float)qb.y));                       \
    for (int s = 1; s < 64; s <<= 1) mm = fmaxf(mm, __shfl_xor(mm, s, 64));  \
    if (0.955f * (float)(kn) >= mm) goto done_lab;                           \
  }

  STEP(0) STEP(1) STEP(2) STEP(3) STEP(4) STEP(5) STEP(6) STEP(7) STEP(8)
  CHECK(9)
  STEP(9) STEP(10) STEP(11) STEP(12)
  CHECK(13)
  STEP(13) STEP(14) STEP(15) STEP(16)
  CHECK(17)
  STEP(17) STEP(18) STEP(19) STEP(20)
  CHECK(21)
  STEP(21) STEP(22) STEP(23) STEP(24)
done_lab:;

  h2 amA = __builtin_elementwise_min(a0, a1);
  h2 amB = __builtin_elementwise_min(b0, b1);
  float d0 = (float)amA.x, d1 = (float)amA.y;
  float d2 = (float)amB.x, d3 = (float)amB.y;

  float w0 = __expf(d0 * (-1.0f / 3.0f)) + 0.1f;
  float w1 = __expf(d1 * (-1.0f / 3.0f)) + 0.1f;
  float w2 = __expf(d2 * (-1.0f / 3.0f)) + 0.1f;
  float w3 = __expf(d3 * (-1.0f / 3.0f)) + 0.1f;

  float t0 = (float)((mw0 >> sh) & 1u);
  float t1 = (float)((mw1 >> sh) & 1u);
  float t2 = (float)((mw2 >> sh) & 1u);
  float t3 = (float)((mw3 >> sh) & 1u);

  L0 = fminf(fmaxf(L0, -16.118095f), 16.118095f);
  L1 = fminf(fmaxf(L1, -16.118095f), 16.118095f);
  L2 = fminf(fmaxf(L2, -16.118095f), 16.118095f);
  L3 = fminf(fmaxf(L3, -16.118095f), 16.118095f);
  float bce0 = fmaxf(L0, 0.0f) - L0 * t0 + __logf(1.0f + __expf(-fabsf(L0)));
  float bce1 = fmaxf(L1, 0.0f) - L1 * t1 + __logf(1.0f + __expf(-fabsf(L1)));
  float bce2 = fmaxf(L2, 0.0f) - L2 * t2 + __logf(1.0f + __expf(-fabsf(L2)));
  float bce3 = fmaxf(L3, 0.0f) - L3 * t3 + __logf(1.0f + __expf(-fabsf(L3)));
  float val = bce0 * w0 + bce1 * w1 + bce2 * w2 + bce3 * w3;

#pragma unroll
  for (int s = 32; s; s >>= 1) val += __shfl_down(val, s, 64);
  if ((tx & 63) == 0) red[tx >> 6] = val;
  __syncthreads();
  if (tx == 0)
    partial[(((b << 7) + by) << 1) + cx] = red[0] + red[1] + red[2] + red[3];
}

// ---------------------------------------------------------------------------
// K2: deterministic final reduction (double accumulation) -> mean.
// ---------------------------------------------------------------------------
__global__ __launch_bounds__(1024) void k_final(
    const float* __restrict__ partial, float* __restrict__ out) {
  __shared__ double red[1024];
  double s = 0.0;
  for (int idx = threadIdx.x; idx < Bn * 256; idx += 1024)
    s += (double)partial[idx];
  red[threadIdx.x] = s;
  __syncthreads();
  for (int st = 512; st; st >>= 1) {
    if (threadIdx.x < st) red[threadIdx.x] += red[threadIdx.x + st];
    __syncthreads();
  }
  if (threadIdx.x == 0)
    out[0] = (float)(red[0] / (double)((size_t)Bn * Hn * Wn));
}

extern "C" void kernel_launch(void* const* d_in, const int* in_sizes, int n_in,
                              void* d_out, int out_size, void* d_ws, size_t ws_size,
                              hipStream_t stream) {
  const float* inputs = (const float*)d_in[0];
  const float* targets = (const float*)d_in[1];
  float* out = (float*)d_out;

  unsigned char* ws = (unsigned char*)d_ws;
  unsigned int* mbits = (unsigned int*)ws;                        // 512 KB
  unsigned int* cbits = (unsigned int*)(ws + (512 << 10));        // 512 KB
  float* partial = (float*)(ws + (1 << 20));                      // 16 KB

  hipLaunchKernelGGL(k_prep, dim3(Bn * 16), dim3(1024), 0, stream, targets,
                     mbits, cbits);
  {
    dim3 blk(256, 1, 1), grd(2, Hn / 4, Bn);
    hipLaunchKernelGGL(k_loss, grd, blk, 0, stream, inputs, mbits, cbits,
                       partial);
  }
  hipLaunchKernelGGL(k_final, dim3(1), dim3(1024), 0, stream, partial, out);
}